// Round 1
// baseline (459.169 us; speedup 1.0000x reference)
//
#include <hip/hip_runtime.h>
#include <hip/hip_bf16.h>

#define GG   256
#define NPGD 192
#define NN   (GG*NPGD)    // 49152 nodes
#define DDIM 128
#define EE   786432
#define HH   8

typedef __attribute__((ext_vector_type(8))) short short8;
typedef __attribute__((ext_vector_type(4))) float f32x4;

__device__ __forceinline__ float bn_rsq() { return 0.9999950000374996f; } // 1/sqrt(1+1e-5)

// ---------------- CSR build ----------------
__global__ __launch_bounds__(256) void k_hist(const int* __restrict__ dst, int* __restrict__ cnt) {
    int e = blockIdx.x * 256 + threadIdx.x;
    if (e < EE) atomicAdd(&cnt[dst[e]], 1);
}

__global__ __launch_bounds__(1024) void k_scan(const int* __restrict__ cnt,
                                               int* __restrict__ offp, int* __restrict__ cur) {
    __shared__ int part[1024];
    const int t = threadIdx.x;
    const int base = t * 48;
    int s = 0;
    for (int i = 0; i < 48; ++i) s += cnt[base + i];
    part[t] = s;
    __syncthreads();
    for (int d = 1; d < 1024; d <<= 1) {
        int v = (t >= d) ? part[t - d] : 0;
        __syncthreads();
        part[t] += v;
        __syncthreads();
    }
    int pre = (t == 0) ? 0 : part[t - 1];
    for (int i = 0; i < 48; ++i) {
        int cv = cnt[base + i];
        offp[base + i] = pre;
        cur[base + i] = pre;
        pre += cv;
    }
    if (t == 1023) offp[NN] = pre;
}

__global__ __launch_bounds__(256) void k_scatter(const int* __restrict__ dst,
                                                 int* __restrict__ cur, int* __restrict__ eid) {
    int e = blockIdx.x * 256 + threadIdx.x;
    if (e < EE) {
        int p = atomicAdd(&cur[dst[e]], 1);
        eid[p] = e;
    }
}

// ---------------- f32 -> bf16 weight convert ----------------
__global__ __launch_bounds__(256) void k_cvt(const float* __restrict__ s,
                                             __hip_bfloat16* __restrict__ d, int n) {
    int i = (blockIdx.x * 256 + threadIdx.x) * 4;
    if (i >= n) return;
    float4 f = *(const float4*)&s[i];
    d[i]     = __float2bfloat16(f.x);
    d[i + 1] = __float2bfloat16(f.y);
    d[i + 2] = __float2bfloat16(f.z);
    d[i + 3] = __float2bfloat16(f.w);
}

// ---------------- GINE aggregate: z = x + sum_in relu(x[src]+e); also emit x_bf16 ----------------
__global__ __launch_bounds__(256) void k_aggr(
    const float* __restrict__ x, const float* __restrict__ ea,
    const int* __restrict__ src, const int* __restrict__ offp, const int* __restrict__ eid,
    __hip_bfloat16* __restrict__ z, __hip_bfloat16* __restrict__ xb)
{
    const int w = threadIdx.x >> 6, l = threadIdx.x & 63;
    const int v = blockIdx.x * 4 + w;
    const int c = l * 2;
    const int b = offp[v], e = offp[v + 1];
    float ax = 0.f, ay = 0.f;
    for (int i = b; i < e; ++i) {
        const int ed = eid[i];
        const int s  = src[ed];
        const float2 ev = *(const float2*)&ea[(size_t)ed * DDIM + c];
        const float2 xv = *(const float2*)&x[(size_t)s * DDIM + c];
        ax += fmaxf(ev.x + xv.x, 0.f);
        ay += fmaxf(ev.y + xv.y, 0.f);
    }
    const float2 xv = *(const float2*)&x[(size_t)v * DDIM + c];
    __hip_bfloat162 zz, xx;
    zz.x = __float2bfloat16(xv.x + ax); zz.y = __float2bfloat16(xv.y + ay);
    xx.x = __float2bfloat16(xv.x);      xx.y = __float2bfloat16(xv.y);
    *(__hip_bfloat162*)&z[(size_t)v * DDIM + c]  = zz;
    *(__hip_bfloat162*)&xb[(size_t)v * DDIM + c] = xx;
}

// ---------------- generic bf16 MFMA GEMM: out = epilogue(A[N,K] @ W[OUTD,K]^T + bias) ----------------
// MODE 0: relu -> bf16            (GIN layer1, FFN layer1)
// MODE 1: bn1l(x + .) -> bf16     (GIN layer2 -> h_local)
// MODE 2: bias only -> bf16       (in_proj; blockIdx.y selects q/k/v chunk)
// MODE 3: bn1g(x + .) + h_local -> bf16   (out_proj -> h)
// MODE 4: bn2(h + .) -> f32       (FFN layer2 -> d_out)
template<int K, int OUTD, int MODE>
__global__ __launch_bounds__(256) void k_gemm(
    const __hip_bfloat16* __restrict__ A, int lda,
    const __hip_bfloat16* __restrict__ W,
    const float* __restrict__ bias,
    void* __restrict__ out, int ldo,
    const float* __restrict__ xres,
    const __hip_bfloat16* __restrict__ resb,
    const float* __restrict__ bng, const float* __restrict__ bnb)
{
    constexpr int KP = K + 8;                  // +16B pad per row: 2-way LDS conflict only
    __shared__ __hip_bfloat16 wl[OUTD * KP];
    const int tid = threadIdx.x;
    const int cb = blockIdx.y * OUTD;          // column base (in_proj chunks)
    W += (size_t)cb * K;
    bias += cb;
    for (int i = tid; i < OUTD * K / 8; i += 256) {
        int r = i / (K / 8), kc = i % (K / 8);
        *(uint4*)&wl[r * KP + kc * 8] = *(const uint4*)&W[(size_t)r * K + kc * 8];
    }
    __syncthreads();

    const int l = tid & 63, w = tid >> 6;
    const int row0 = blockIdx.x * 64 + w * 16;
    const int cl = l & 15;
    const int kg = (l >> 4) * 8;
    const int rg = (l >> 4) * 4;

    short8 af[K / 32];
#pragma unroll
    for (int f = 0; f < K / 32; ++f)
        af[f] = *(const short8*)&A[(size_t)(row0 + cl) * lda + f * 32 + kg];

#pragma unroll
    for (int ct = 0; ct < OUTD / 16; ++ct) {
        f32x4 acc = {0.f, 0.f, 0.f, 0.f};
#pragma unroll
        for (int f = 0; f < K / 32; ++f) {
            short8 bf = *(const short8*)&wl[(ct * 16 + cl) * KP + f * 32 + kg];
            acc = __builtin_amdgcn_mfma_f32_16x16x32_bf16(af[f], bf, acc, 0, 0, 0);
        }
        const int c = cb + ct * 16 + cl;
        const float bv = bias[ct * 16 + cl];
#pragma unroll
        for (int j = 0; j < 4; ++j) {
            const int r = row0 + rg + j;
            float v = acc[j] + bv;
            if constexpr (MODE == 0) {
                ((__hip_bfloat16*)out)[(size_t)r * ldo + c] = __float2bfloat16(fmaxf(v, 0.f));
            } else if constexpr (MODE == 1) {
                v += xres[(size_t)r * DDIM + c];
                v = bng[c] * v * bn_rsq() + bnb[c];
                ((__hip_bfloat16*)out)[(size_t)r * ldo + c] = __float2bfloat16(v);
            } else if constexpr (MODE == 2) {
                ((__hip_bfloat16*)out)[(size_t)r * ldo + c] = __float2bfloat16(v);
            } else if constexpr (MODE == 3) {
                v += xres[(size_t)r * DDIM + c];
                v = bng[c] * v * bn_rsq() + bnb[c];
                v += __bfloat162float(resb[(size_t)r * DDIM + c]);
                ((__hip_bfloat16*)out)[(size_t)r * ldo + c] = __float2bfloat16(v);
            } else {
                v += __bfloat162float(resb[(size_t)r * DDIM + c]);
                v = bng[c] * v * bn_rsq() + bnb[c];
                ((float*)out)[(size_t)r * ldo + c] = v;
            }
        }
    }
}

// ---------------- fused attention per (graph, head) ----------------
__global__ __launch_bounds__(256) void k_attn(const __hip_bfloat16* __restrict__ qkv,
                                              __hip_bfloat16* __restrict__ o)
{
    const int g = blockIdx.x, h = blockIdx.y;
    __shared__ __hip_bfloat16 Kl[NPGD * 24];     // K rows (dh=16) padded to 24
    __shared__ __hip_bfloat16 Vt[16 * 200];      // V^T [d][k] padded to 200
    __shared__ __hip_bfloat16 Pl[4][16 * 200];   // per-wave P [q][k] padded
    const int tid = threadIdx.x;
    const size_t gbase = (size_t)g * NPGD * 384;

    for (int i = tid; i < 384; i += 256) {       // stage K: 192 rows x 16 elems
        int r = i >> 1, hf = i & 1;
        *(uint4*)&Kl[r * 24 + hf * 8] =
            *(const uint4*)&qkv[gbase + (size_t)r * 384 + 128 + h * 16 + hf * 8];
    }
    for (int i = tid; i < 3072; i += 256) {      // stage V^T
        int k = i >> 4, d = i & 15;
        Vt[d * 200 + k] = qkv[gbase + (size_t)k * 384 + 256 + h * 16 + d];
    }
    __syncthreads();

    const int w = tid >> 6, l = tid & 63;
    const int cl = l & 15, gq = l >> 4;

    for (int it = 0; it < 3; ++it) {
        const int qt = w + it * 4;
        short8 aq = {0, 0, 0, 0, 0, 0, 0, 0};
        if (gq < 2)
            aq = *(const short8*)&qkv[gbase + (size_t)(qt * 16 + cl) * 384 + h * 16 + gq * 8];

        f32x4 s[12];
#pragma unroll
        for (int kt = 0; kt < 12; ++kt) {
            short8 bk = {0, 0, 0, 0, 0, 0, 0, 0};
            if (gq < 2)
                bk = *(const short8*)&Kl[(kt * 16 + cl) * 24 + gq * 8];
            f32x4 zz = {0.f, 0.f, 0.f, 0.f};
            s[kt] = __builtin_amdgcn_mfma_f32_16x16x32_bf16(aq, bk, zz, 0, 0, 0);
        }
#pragma unroll
        for (int kt = 0; kt < 12; ++kt) s[kt] *= 0.25f;   // 1/sqrt(dh)

        // softmax over k (cols spread across cl lanes and the 12 tiles)
        float mj[4], sj[4];
#pragma unroll
        for (int j = 0; j < 4; ++j) {
            float mm = -3.0e38f;
#pragma unroll
            for (int kt = 0; kt < 12; ++kt) mm = fmaxf(mm, s[kt][j]);
            mm = fmaxf(mm, __shfl_xor(mm, 1));
            mm = fmaxf(mm, __shfl_xor(mm, 2));
            mm = fmaxf(mm, __shfl_xor(mm, 4));
            mm = fmaxf(mm, __shfl_xor(mm, 8));
            mj[j] = mm;
        }
#pragma unroll
        for (int j = 0; j < 4; ++j) {
            float sum = 0.f;
#pragma unroll
            for (int kt = 0; kt < 12; ++kt) {
                float p = __expf(s[kt][j] - mj[j]);
                s[kt][j] = p;
                sum += p;
            }
            sum += __shfl_xor(sum, 1);
            sum += __shfl_xor(sum, 2);
            sum += __shfl_xor(sum, 4);
            sum += __shfl_xor(sum, 8);
            sj[j] = 1.f / sum;
        }
#pragma unroll
        for (int kt = 0; kt < 12; ++kt)
#pragma unroll
            for (int j = 0; j < 4; ++j)
                Pl[w][(gq * 4 + j) * 200 + kt * 16 + cl] = __float2bfloat16(s[kt][j] * sj[j]);
        __syncthreads();

        f32x4 oa = {0.f, 0.f, 0.f, 0.f};
#pragma unroll
        for (int kt = 0; kt < 6; ++kt) {
            short8 ap = *(const short8*)&Pl[w][cl * 200 + kt * 32 + gq * 8];
            short8 av = *(const short8*)&Vt[cl * 200 + kt * 32 + gq * 8];
            oa = __builtin_amdgcn_mfma_f32_16x16x32_bf16(ap, av, oa, 0, 0, 0);
        }
#pragma unroll
        for (int j = 0; j < 4; ++j)
            o[((size_t)g * NPGD + qt * 16 + gq * 4 + j) * DDIM + h * 16 + cl] = __float2bfloat16(oa[j]);
        __syncthreads();
    }
}

// ---------------- launch ----------------
extern "C" void kernel_launch(void* const* d_in, const int* in_sizes, int n_in,
                              void* d_out, int out_size, void* d_ws, size_t ws_size,
                              hipStream_t stream) {
    (void)in_sizes; (void)n_in; (void)out_size; (void)ws_size;
    const float* x    = (const float*)d_in[0];
    const float* ea   = (const float*)d_in[1];
    const int*   ei   = (const int*)d_in[2];
    const float* gw1  = (const float*)d_in[3];
    const float* gb1  = (const float*)d_in[4];
    const float* gw2  = (const float*)d_in[5];
    const float* gb2  = (const float*)d_in[6];
    const float* ipw  = (const float*)d_in[7];
    const float* ipb  = (const float*)d_in[8];
    const float* opw  = (const float*)d_in[9];
    const float* opb  = (const float*)d_in[10];
    const float* b1lg = (const float*)d_in[11];
    const float* b1lb = (const float*)d_in[12];
    const float* b1gg = (const float*)d_in[13];
    const float* b1gb = (const float*)d_in[14];
    const float* b2g  = (const float*)d_in[15];
    const float* b2b  = (const float*)d_in[16];
    const float* fw1  = (const float*)d_in[17];
    const float* fb1  = (const float*)d_in[18];
    const float* fw2  = (const float*)d_in[19];
    const float* fb2  = (const float*)d_in[20];

    char* ws = (char*)d_ws;
    size_t off = 0;
    auto alloc = [&](size_t b) -> char* {
        char* p = ws + off;
        off = (off + b + 255) & ~(size_t)255;
        return p;
    };
    int* cnt  = (int*)alloc((NN + 1) * 4);
    int* offp = (int*)alloc((NN + 1) * 4);
    int* cur  = (int*)alloc((NN + 1) * 4);
    __hip_bfloat16* wbuf = (__hip_bfloat16*)alloc(163840 * 2);
    int* eid  = (int*)alloc((size_t)EE * 4);
    __hip_bfloat16* xb  = (__hip_bfloat16*)alloc((size_t)NN * DDIM * 2);
    __hip_bfloat16* zb  = (__hip_bfloat16*)alloc((size_t)NN * DDIM * 2);  // z, later h
    __hip_bfloat16* g1  = (__hip_bfloat16*)alloc((size_t)NN * DDIM * 2);  // gin hidden, later attn out
    __hip_bfloat16* hl  = (__hip_bfloat16*)alloc((size_t)NN * DDIM * 2);  // h_local
    __hip_bfloat16* qkv = (__hip_bfloat16*)alloc((size_t)NN * 384 * 2);   // qkv, later ffn hidden

    __hip_bfloat16* w1b  = wbuf;
    __hip_bfloat16* w2b  = wbuf + 16384;
    __hip_bfloat16* ipwb = wbuf + 32768;
    __hip_bfloat16* opwb = wbuf + 81920;
    __hip_bfloat16* f1b  = wbuf + 98304;
    __hip_bfloat16* f2bw = wbuf + 131072;

    const int* srcI = ei;
    const int* dstI = ei + EE;

    hipMemsetAsync(cnt, 0, (NN + 1) * 4, stream);
    k_hist<<<EE / 256, 256, 0, stream>>>(dstI, cnt);
    k_scan<<<1, 1024, 0, stream>>>(cnt, offp, cur);
    k_scatter<<<EE / 256, 256, 0, stream>>>(dstI, cur, eid);
    k_cvt<<<16, 256, 0, stream>>>(gw1, w1b, 16384);
    k_cvt<<<16, 256, 0, stream>>>(gw2, w2b, 16384);
    k_cvt<<<48, 256, 0, stream>>>(ipw, ipwb, 49152);
    k_cvt<<<16, 256, 0, stream>>>(opw, opwb, 16384);
    k_cvt<<<32, 256, 0, stream>>>(fw1, f1b, 32768);
    k_cvt<<<32, 256, 0, stream>>>(fw2, f2bw, 32768);
    k_aggr<<<NN / 4, 256, 0, stream>>>(x, ea, srcI, offp, eid, zb, xb);
    // GIN MLP
    k_gemm<128, 128, 0><<<NN / 64, 256, 0, stream>>>(zb, 128, w1b, gb1, g1, 128,
                                                     nullptr, nullptr, nullptr, nullptr);
    k_gemm<128, 128, 1><<<NN / 64, 256, 0, stream>>>(g1, 128, w2b, gb2, hl, 128,
                                                     x, nullptr, b1lg, b1lb);
    // in_proj (3 chunks of 128 cols via blockIdx.y)
    k_gemm<128, 128, 2><<<dim3(NN / 64, 3), 256, 0, stream>>>(xb, 128, ipwb, ipb, qkv, 384,
                                                              nullptr, nullptr, nullptr, nullptr);
    // attention -> o (reuse g1)
    k_attn<<<dim3(GG, HH), 256, 0, stream>>>(qkv, g1);
    // out_proj + bn1g + merge with h_local -> h (reuse zb)
    k_gemm<128, 128, 3><<<NN / 64, 256, 0, stream>>>(g1, 128, opwb, opb, zb, 128,
                                                     x, hl, b1gg, b1gb);
    // FFN
    k_gemm<128, 256, 0><<<NN / 64, 256, 0, stream>>>(zb, 128, f1b, fb1, qkv, 256,
                                                     nullptr, nullptr, nullptr, nullptr);
    k_gemm<256, 128, 4><<<NN / 64, 256, 0, stream>>>(qkv, 256, f2bw, fb2, d_out, 128,
                                                     nullptr, zb, b2g, b2b);
}